// Round 12
// baseline (965.296 us; speedup 1.0000x reference)
//
#include <hip/hip_runtime.h>
#include <cstdint>
#include <cstddef>

#define HDIM 2048
#define VOCAB 32000
#define BT 4096      // B*T tokens
#define NVB 125      // VOCAB / 256
#define BETA_F 0.1f
#define SCALE_X 16.0f
#define SCALE_W 64.0f
#define INV_SC (1.0f / (SCALE_X * SCALE_W))
#define ID_SCALE 0x7f7f7f7f  // E8M0 identity (2^0) x4

typedef float f32x16 __attribute__((ext_vector_type(16)));
typedef int i32x4v __attribute__((ext_vector_type(4)));
typedef int i32x8v __attribute__((ext_vector_type(8)));

// ---------------------------------------------------------------- helpers
__device__ __forceinline__ void async_lds16(const void* g, void* l) {
  __builtin_amdgcn_global_load_lds(
      (__attribute__((address_space(1))) void*)g,
      (__attribute__((address_space(3))) void*)l,
      16, 0, 0);
}

#define BAR() __builtin_amdgcn_s_barrier()
#define SCHED0() __builtin_amdgcn_sched_barrier(0)
#define VMCNT(n) do { asm volatile("s_waitcnt vmcnt(" #n ")" ::: "memory"); \
                      __builtin_amdgcn_sched_barrier(0); } while (0)

// ---------------------------------------------------------------- cast fp32 -> fp8 e4m3 (16 elems/thread), scaled
__global__ void cast_fp8_kernel(const float* __restrict__ src,
                                uint4* __restrict__ dst, int n16, float scale) {
  int i = blockIdx.x * blockDim.x + threadIdx.x;
  int stride = gridDim.x * blockDim.x;
  for (; i < n16; i += stride) {
    const float4* s = (const float4*)src + (size_t)i * 4;
    uint4 o;
    {
      float4 a = s[0];
      int r = __builtin_amdgcn_cvt_pk_fp8_f32(a.x * scale, a.y * scale, 0, false);
      o.x = __builtin_amdgcn_cvt_pk_fp8_f32(a.z * scale, a.w * scale, r, true);
    }
    {
      float4 a = s[1];
      int r = __builtin_amdgcn_cvt_pk_fp8_f32(a.x * scale, a.y * scale, 0, false);
      o.y = __builtin_amdgcn_cvt_pk_fp8_f32(a.z * scale, a.w * scale, r, true);
    }
    {
      float4 a = s[2];
      int r = __builtin_amdgcn_cvt_pk_fp8_f32(a.x * scale, a.y * scale, 0, false);
      o.z = __builtin_amdgcn_cvt_pk_fp8_f32(a.z * scale, a.w * scale, r, true);
    }
    {
      float4 a = s[3];
      int r = __builtin_amdgcn_cvt_pk_fp8_f32(a.x * scale, a.y * scale, 0, false);
      o.w = __builtin_amdgcn_cvt_pk_fp8_f32(a.z * scale, a.w * scale, r, true);
    }
    dst[i] = o;
  }
}

// ---------------------------------------------------------------- 256x256 MX-fp8 GEMM + LSE partials, 16 waves
// R11's verified 16-wave / 8-phase / 2-barrier schedule with the MFMA swapped
// to mfma_scale_f32_32x32x64_f8f6f4 (identity scales = numerically identical
// to non-scaled fp8, R6/R7-verified absmax 0; 2x the MFMA rate). Wave-tile
// 64x64: acc = 4 x f32x16 = 64 VGPR (same as R11); 4 MFMA + 8 ds_read_b128
// per wave per K-tile; 2 stage ops per wave per K-tile.
//
// LDS half-tile (8 KiB, 128 rows x 64 B) storage map (R7-verified: 0 bank
// conflicts, absmax 0): chunk (r, c) [c = 16B K-chunk 0..3] stored at
//   offset = (r>>5)*2048 + (c&1)*1024 + (r&15)*64 + (c>>1)*32 + ((r>>4)&1)*16
//            ^ ((r>>3 & 1) << 5)
// Read: lane l (h=l>>5) reads chunks {2h,2h+1} of row (l&31)+base as two
// ds_read_b128 at phys p, p+1024 (conflict-free quarter-wave pattern).
// Staging: waves 0..7 fill half 0, waves 8..15 half 1 (w'=w&7, granule
// w'*1024), source = R7's inverse map with srow += (w>>3)*128.
//
// NOTE 1024-thread block REQUIRES <=128 VGPR/wave. acc 64 + frags 32 + addr
// ~20 fits. Spill tripwire: WRITE_SIZE balloons (R4/R8). No VGPR cap beyond.
__global__ __launch_bounds__(1024) void gemm_lse256(
    const unsigned char* __restrict__ Xq,
    const unsigned char* __restrict__ Xrq,
    const unsigned char* __restrict__ Wq,
    const unsigned char* __restrict__ Wrq,
    float2* __restrict__ part) {
  __shared__ __align__(16) char lds[2][2][2][8192];  // [buf][A/B][half]

  const int tid = threadIdx.x;
  const int lane = tid & 63;
  const int w = tid >> 6;        // wave 0..15
  const int wm = w >> 2;         // 0..3 : M 64-row band
  const int wn = w & 3;          // 0..3 : N 64-col band
  const int which = blockIdx.y;  // 0 = policy, 1 = reference

  // XCD-aware bijective swizzle: 2000 blocks = 8 XCDs x 250, mb fastest within chunk.
  const int lin = blockIdx.x;
  const int nl = (lin & 7) * 250 + (lin >> 3);
  const int mb = nl & 15;        // 0..15
  const int nb = nl >> 4;        // 0..124

  const unsigned char* A = which ? Xrq : Xq;
  const unsigned char* B = which ? Wrq : Wq;
  float2* pp = part + (size_t)which * BT * NVB;

  // ---- staging addressing (R7 inverse map; wave w fills half w>>3, granule (w&7)*1024)
  const int wp = w & 7;
  const int lp = lane ^ (((lane >> 5) & 1) << 1);
  const int srow = (w >> 3) * 128 + (wp >> 1) * 32 + (lp & 1) * 16 + ((lp >> 2) & 15);
  const int scol = ((lp >> 1) & 1) * 32 + (wp & 1) * 16;
  const unsigned char* Ag = A + (size_t)(mb * 256 + srow) * HDIM + scol;
  const unsigned char* Bg = B + (size_t)(nb * 256 + srow) * HDIM + scol;

#define STAGE_AB(buf, T) do {                                                 \
    async_lds16(Ag + (size_t)(T) * 64, &lds[buf][0][w >> 3][0] + wp * 1024);  \
    async_lds16(Bg + (size_t)(T) * 64, &lds[buf][1][w >> 3][0] + wp * 1024);  \
  } while (0)

  // ---- fragment read: chunks {2h, 2h+1} = two swizzled ds_read_b128 (p, p+1024)
  const int l31 = lane & 31;
  const int khalf = (lane >> 5) * 32;
#define FRAG32(dst, halfptr, row) do {                                        \
    int _r = (row);                                                           \
    int _p = ((((_r >> 5) << 11) + ((_r & 15) << 6) + khalf +                 \
               (((_r >> 4) & 1) << 4)) ^ (((_r >> 3) & 1) << 5));             \
    i32x4v _lo = *(const i32x4v*)((halfptr) + _p);                            \
    i32x4v _hi = *(const i32x4v*)((halfptr) + _p + 1024);                     \
    dst = (i32x8v){_lo[0], _lo[1], _lo[2], _lo[3],                            \
                   _hi[0], _hi[1], _hi[2], _hi[3]};                           \
  } while (0)

  const char* Ah[2] = { &lds[0][0][wm >> 1][0], &lds[1][0][wm >> 1][0] };
  const char* Bh[2] = { &lds[0][1][wn >> 1][0], &lds[1][1][wn >> 1][0] };
  const int arow = (wm & 1) * 64 + l31;
  const int brow = (wn & 1) * 64 + l31;

  f32x16 acc00 = {}, acc01 = {}, acc10 = {}, acc11 = {};
  i32x8v aF0, aF1, bF0, bF1;

#define MFMA1(ACC, AF, BF) do {                                               \
    __builtin_amdgcn_s_setprio(1);                                            \
    ACC = __builtin_amdgcn_mfma_scale_f32_32x32x64_f8f6f4(                    \
        AF, BF, ACC, 0, 0, 0, ID_SCALE, 0, ID_SCALE);                         \
    __builtin_amdgcn_s_setprio(0);                                            \
  } while (0)

  // ---- prologue: stage tiles 0 (buf0) and 1 (buf1); prefetch aF0/bF0 of t0 ----
  STAGE_AB(0, 0);
  STAGE_AB(1, 1);
  VMCNT(2);                      // tile0's 2 ops landed (tile1's 2 in flight)
  BAR(); SCHED0();
  FRAG32(aF0, Ah[0], arow);
  FRAG32(bF0, Bh[0], brow);
  SCHED0();

  // ---- main loop: 16 iterations, 2 K-tiles each ----
  for (int i = 0; i < 16; ++i) {
    const int se = (2 * i + 2 > 30) ? 30 : 2 * i + 2;  // even tile -> buf0
    const int so = (2 * i + 3 > 31) ? 31 : 2 * i + 3;  // odd  tile -> buf1

    // P1: issue bF1(t0); MFMA acc00
    FRAG32(bF1, Bh[0], brow + 32); SCHED0();
    MFMA1(acc00, aF0, bF0); SCHED0();
    // P2: issue aF1(t0); MFMA acc01
    FRAG32(aF1, Ah[0], arow + 32); SCHED0();
    MFMA1(acc01, aF0, bF1); SCHED0();
    // P3: MFMA acc10
    MFMA1(acc10, aF1, bF0); SCHED0();
    // P4: handoff -> buf1. t1's 2 stages landed (vmcnt); every wave's buf0
    // reads completed before its own lgkm waits => staging buf0 after BAR is
    // WAR-safe. Then prefetch t1's first fragments.
    VMCNT(0);
    BAR(); SCHED0();
    STAGE_AB(0, se);
    FRAG32(aF0, Ah[1], arow);
    FRAG32(bF0, Bh[1], brow); SCHED0();
    MFMA1(acc11, aF1, bF1); SCHED0();          // operands already in regs

    // P5: issue bF1(t1); MFMA acc00
    FRAG32(bF1, Bh[1], brow + 32); SCHED0();
    MFMA1(acc00, aF0, bF0); SCHED0();
    // P6: issue aF1(t1); MFMA acc01
    FRAG32(aF1, Ah[1], arow + 32); SCHED0();
    MFMA1(acc01, aF0, bF1); SCHED0();
    // P7: MFMA acc10
    MFMA1(acc10, aF1, bF0); SCHED0();
    // P8: handoff -> buf0 (se's stages landed; buf1 reads retired => stage so)
    VMCNT(0);
    BAR(); SCHED0();
    STAGE_AB(1, so);
    FRAG32(aF0, Ah[0], arow);
    FRAG32(bF0, Bh[0], brow); SCHED0();
    MFMA1(acc11, aF1, bF1); SCHED0();
  }
  VMCNT(0);                      // drain tail re-stages before LDS reuse
  BAR(); SCHED0();

  // ---- fused LSE epilogue over this block's 256 vocab cols ----
  // 32x32 C/D layout (R7-verified): col = lane&31,
  // row = (reg&3) + 8*(reg>>2) + 4*(lane>>5). Un-scale by INV_SC.
  float* red = (float*)&lds[0][0][0][0];   // m: [wn*256+row], s: [1024 + wn*256+row]
#pragma unroll
  for (int mi = 0; mi < 2; ++mi) {
    const f32x16& a0 = mi ? acc10 : acc00;
    const f32x16& a1 = mi ? acc11 : acc01;
#pragma unroll
    for (int r = 0; r < 16; ++r) {
      float v0 = a0[r] * INV_SC;
      float v1 = a1[r] * INV_SC;
      float m = fmaxf(v0, v1);
#pragma unroll
      for (int o = 1; o < 32; o <<= 1) m = fmaxf(m, __shfl_xor(m, o, 64));
      float s = __expf(v0 - m) + __expf(v1 - m);
#pragma unroll
      for (int o = 1; o < 32; o <<= 1) s += __shfl_xor(s, o, 64);
      if (l31 == 0) {
        int row = wm * 64 + mi * 32 + (r & 3) + 8 * (r >> 2) + 4 * (lane >> 5);
        red[wn * 256 + row] = m;
        red[1024 + wn * 256 + row] = s;
      }
    }
  }
  __syncthreads();
  if (tid < 256) {
    float m0 = red[tid], m1 = red[256 + tid], m2 = red[512 + tid], m3 = red[768 + tid];
    float M = fmaxf(fmaxf(m0, m1), fmaxf(m2, m3));
    float S = red[1024 + tid] * __expf(m0 - M) + red[1280 + tid] * __expf(m1 - M) +
              red[1536 + tid] * __expf(m2 - M) + red[1792 + tid] * __expf(m3 - M);
    pp[(size_t)(mb * 256 + tid) * NVB + nb] = make_float2(M, S);
  }
#undef STAGE_AB
#undef FRAG32
#undef MFMA1
}

// ---------------------------------------------------------------- exact fp32 target logit: dot(x, W[y])
__global__ void target_logit(const float* __restrict__ x, const float* __restrict__ xr,
                             const float* __restrict__ W, const float* __restrict__ Wr,
                             const int* __restrict__ y, float* __restrict__ tlog) {
  int wid = (blockIdx.x * blockDim.x + threadIdx.x) >> 6;  // 0..8191
  int lane = threadIdx.x & 63;
  int which = wid >> 12;
  int tok = wid & 4095;
  int yy = y[tok];
  int ys = (yy == -100) ? 0 : yy;
  const float* xv = (which ? xr : x) + (size_t)tok * HDIM;
  const float* wv = (which ? Wr : W) + (size_t)ys * HDIM;
  const float4* x4 = (const float4*)xv;
  const float4* w4 = (const float4*)wv;
  float sum = 0.f;
  for (int i = lane; i < HDIM / 4; i += 64) {
    float4 a = x4[i], b = w4[i];
    sum += a.x * b.x + a.y * b.y + a.z * b.z + a.w * b.w;
  }
#pragma unroll
  for (int o = 1; o < 64; o <<= 1) sum += __shfl_xor(sum, o, 64);
  if (lane == 0) tlog[wid] = sum;
}

// ---------------------------------------------------------------- merge partials -> per-token logp
__global__ void lse_combine(const float2* __restrict__ part,
                            const float* __restrict__ tlog,
                            float* __restrict__ ptok) {
  int wid = (blockIdx.x * blockDim.x + threadIdx.x) >> 6;  // 0..8191
  int lane = threadIdx.x & 63;
  const float2* p = part + (size_t)wid * NVB;
  float m = -INFINITY, s = 0.f;
  for (int i = lane; i < NVB; i += 64) {
    float2 v = p[i];
    float M = fmaxf(m, v.x);
    s = s * __expf(m - M) + v.y * __expf(v.x - M);
    m = M;
  }
#pragma unroll
  for (int o = 1; o < 64; o <<= 1) {
    float mo = __shfl_xor(m, o, 64);
    float so = __shfl_xor(s, o, 64);
    float M = fmaxf(m, mo);
    s = s * __expf(m - M) + so * __expf(mo - M);
    m = M;
  }
  if (lane == 0) ptok[wid] = tlog[wid] - (m + logf(s));
}

// ---------------------------------------------------------------- masked per-seq mean + DPO loss
__global__ void final_loss(const float* __restrict__ ptok,
                           const int* __restrict__ y, float* __restrict__ out) {
  __shared__ float rs[256];
  __shared__ float rc[256];
  __shared__ float seq[8];
  int tid = threadIdx.x;
  for (int s = 0; s < 8; ++s) {
    int which = s >> 2, b = s & 3;
    float lsum = 0.f, lcnt = 0.f;
    for (int t = tid; t < 1024; t += 256) {
      int yy = y[b * 1024 + t];
      if (yy != -100) {
        lsum += ptok[which * 4096 + b * 1024 + t];
        lcnt += 1.f;
      }
    }
    rs[tid] = lsum; rc[tid] = lcnt;
    __syncthreads();
    for (int o = 128; o > 0; o >>= 1) {
      if (tid < o) { rs[tid] += rs[tid + o]; rc[tid] += rc[tid + o]; }
      __syncthreads();
    }
    if (tid == 0) seq[s] = rs[0] / rc[0];
    __syncthreads();
  }
  if (tid == 0) {
    float d0 = BETA_F * ((seq[0] - seq[4]) - (seq[2] - seq[6]));
    float d1 = BETA_F * ((seq[1] - seq[5]) - (seq[3] - seq[7]));
    auto sp = [](float a) { return fmaxf(a, 0.f) + log1pf(expf(-fabsf(a))); };
    out[0] = (sp(-d0) + sp(-d1)) * 0.5f;
  }
}

// ---------------------------------------------------------------- launch
extern "C" void kernel_launch(void* const* d_in, const int* in_sizes, int n_in,
                              void* d_out, int out_size, void* d_ws, size_t ws_size,
                              hipStream_t stream) {
  const float* x   = (const float*)d_in[0];
  const float* xr  = (const float*)d_in[1];
  const int*   y   = (const int*)d_in[2];
  const float* Wf  = (const float*)d_in[3];
  const float* Wrf = (const float*)d_in[4];
  float* out = (float*)d_out;

  char* ws = (char*)d_ws;
  size_t off = 0;
  auto alloc = [&](size_t bytes) -> void* {
    void* p = ws + off;
    off = (off + bytes + 255) & ~(size_t)255;
    return p;
  };
  unsigned char* Xq  = (unsigned char*)alloc((size_t)BT * HDIM);
  unsigned char* Xrq = (unsigned char*)alloc((size_t)BT * HDIM);
  unsigned char* Wq  = (unsigned char*)alloc((size_t)VOCAB * HDIM);
  unsigned char* Wrq = (unsigned char*)alloc((size_t)VOCAB * HDIM);
  float2* part = (float2*)alloc((size_t)2 * BT * NVB * sizeof(float2));
  float*  tlog = (float*)alloc((size_t)2 * BT * sizeof(float));
  float*  ptok = (float*)alloc((size_t)2 * BT * sizeof(float));

  cast_fp8_kernel<<<2048, 256, 0, stream>>>(x,  (uint4*)Xq,  BT * HDIM / 16, SCALE_X);
  cast_fp8_kernel<<<2048, 256, 0, stream>>>(xr, (uint4*)Xrq, BT * HDIM / 16, SCALE_X);
  cast_fp8_kernel<<<2048, 256, 0, stream>>>(Wf,  (uint4*)Wq,  VOCAB * HDIM / 16, SCALE_W);
  cast_fp8_kernel<<<2048, 256, 0, stream>>>(Wrf, (uint4*)Wrq, VOCAB * HDIM / 16, SCALE_W);

  dim3 gg(2000, 2);
  gemm_lse256<<<gg, 1024, 0, stream>>>(Xq, Xrq, Wq, Wrq, part);

  target_logit<<<2048, 256, 0, stream>>>(x, xr, Wf, Wrf, y, tlog);
  lse_combine<<<2048, 256, 0, stream>>>(part, tlog, ptok);
  final_loss<<<1, 256, 0, stream>>>(ptok, y, out);
}